// Round 1
// baseline (1142.684 us; speedup 1.0000x reference)
//
#include <hip/hip_runtime.h>
#include <cstdint>
#include <cstddef>

#define NEG_SLOPE 0.01f

// ---- order-preserving float <-> uint encoding for atomicMax on floats ----
__device__ __forceinline__ unsigned f2ord(float f) {
    unsigned b = __float_as_uint(f);
    return (b & 0x80000000u) ? ~b : (b | 0x80000000u);
}
__device__ __forceinline__ float ord2f(unsigned u) {
    return (u & 0x80000000u) ? __uint_as_float(u & 0x7FFFFFFFu)
                             : __uint_as_float(~u);
}

// ---- layer 1 GEMM: z = h[N,128] @ W[128,32], plus s_src/s_dst logits ----
__global__ __launch_bounds__(256) void gemm1_kernel(
    const float* __restrict__ h, const float* __restrict__ W,
    const float* __restrict__ a, float* __restrict__ z,
    float* __restrict__ s_src, float* __restrict__ s_dst, int N)
{
    __shared__ float Wl[128 * 32];
    int tid = threadIdx.x;
    for (int i = tid; i < 128 * 32; i += 256) Wl[i] = W[i];
    __syncthreads();

    int row = blockIdx.x * 8 + (tid >> 5);
    int col = tid & 31;
    if (row >= N) return;

    const float* hp = h + (size_t)row * 128;
    float hv[4];
#pragma unroll
    for (int c = 0; c < 4; c++) hv[c] = hp[c * 32 + col];

    float acc = 0.f;
#pragma unroll
    for (int k = 0; k < 128; k++) {
        float hk = __shfl(hv[k >> 5], k & 31, 32);
        acc += hk * Wl[k * 32 + col];
    }
    z[(size_t)row * 32 + col] = acc;

    float ps = acc * a[col];
    float pd = acc * a[32 + col];
#pragma unroll
    for (int off = 16; off > 0; off >>= 1) {
        ps += __shfl_xor(ps, off, 32);
        pd += __shfl_xor(pd, off, 32);
    }
    if (col == 0) { s_src[row] = ps; s_dst[row] = pd; }
}

// ---- layer 2 GEMM: z = h[N,32] @ W[32,32], plus logits ----
__global__ __launch_bounds__(256) void gemm2_kernel(
    const float* __restrict__ h, const float* __restrict__ W,
    const float* __restrict__ a, float* __restrict__ z,
    float* __restrict__ s_src, float* __restrict__ s_dst, int N)
{
    __shared__ float Wl[32 * 32];
    int tid = threadIdx.x;
    for (int i = tid; i < 32 * 32; i += 256) Wl[i] = W[i];
    __syncthreads();

    int row = blockIdx.x * 8 + (tid >> 5);
    int col = tid & 31;
    if (row >= N) return;

    float hv = h[(size_t)row * 32 + col];
    float acc = 0.f;
#pragma unroll
    for (int k = 0; k < 32; k++)
        acc += __shfl(hv, k, 32) * Wl[k * 32 + col];

    z[(size_t)row * 32 + col] = acc;

    float ps = acc * a[col];
    float pd = acc * a[32 + col];
#pragma unroll
    for (int off = 16; off > 0; off >>= 1) {
        ps += __shfl_xor(ps, off, 32);
        pd += __shfl_xor(pd, off, 32);
    }
    if (col == 0) { s_src[row] = ps; s_dst[row] = pd; }
}

// ---- layer 3 "GEMM": z = h[N,32] @ W[32,1], logits are scalar scales ----
__global__ __launch_bounds__(256) void gemm3_kernel(
    const float* __restrict__ h, const float* __restrict__ W,
    const float* __restrict__ a, float* __restrict__ z,
    float* __restrict__ s_src, float* __restrict__ s_dst, int N)
{
    int i = blockIdx.x * 256 + threadIdx.x;
    if (i >= N) return;
    const float4* hp = (const float4*)(h + (size_t)i * 32);
    const float4* wp = (const float4*)W;
    float acc = 0.f;
#pragma unroll
    for (int c = 0; c < 8; c++) {
        float4 v = hp[c];
        float4 w = wp[c];
        acc += v.x * w.x + v.y * w.y + v.z * w.z + v.w * w.w;
    }
    z[i] = acc;
    s_src[i] = acc * a[0];
    s_dst[i] = acc * a[1];
}

// ---- edge pass 1: e = leaky_relu(s_src[src]+s_dst[dst]); segment max ----
__global__ __launch_bounds__(256) void edge_max_kernel(
    const int* __restrict__ src, const int* __restrict__ dst,
    const float* __restrict__ s_src, const float* __restrict__ s_dst,
    float* __restrict__ e_ws, unsigned* __restrict__ mord, int E)
{
    int k = blockIdx.x * 256 + threadIdx.x;
    if (k >= E) return;
    int s = src[k], d = dst[k];
    float e = s_src[s] + s_dst[d];
    e = (e > 0.f) ? e : NEG_SLOPE * e;
    e_ws[k] = e;
    atomicMax(&mord[d], f2ord(e));
}

// ---- edge pass 2 (d_out=32): w=exp(e-m); accum[dst,:] += w*z[src,:] ----
__global__ __launch_bounds__(256) void edge_agg32_kernel(
    const int* __restrict__ src, const int* __restrict__ dst,
    const float* __restrict__ e_ws, const unsigned* __restrict__ mord,
    const float* __restrict__ z, float* __restrict__ accum,
    float* __restrict__ denom, int E)
{
    long long t = (long long)blockIdx.x * 256 + threadIdx.x;
    int k = (int)(t >> 5);
    int j = (int)(t & 31);
    if (k >= E) return;
    int s = src[k], d = dst[k];
    float m = ord2f(mord[d]);
    float w = __expf(e_ws[k] - m);
    if (j == 0) atomicAdd(&denom[d], w);
    atomicAdd(&accum[(size_t)d * 32 + j], w * z[(size_t)s * 32 + j]);
}

// ---- edge pass 2 (d_out=1) ----
__global__ __launch_bounds__(256) void edge_agg1_kernel(
    const int* __restrict__ src, const int* __restrict__ dst,
    const float* __restrict__ e_ws, const unsigned* __restrict__ mord,
    const float* __restrict__ z, float* __restrict__ accum,
    float* __restrict__ denom, int E)
{
    int k = blockIdx.x * 256 + threadIdx.x;
    if (k >= E) return;
    int s = src[k], d = dst[k];
    float w = __expf(e_ws[k] - ord2f(mord[d]));
    atomicAdd(&denom[d], w);
    atomicAdd(&accum[d], w * z[s]);
}

// ---- finalize (d_out=32): h = relu(accum/denom) ----
__global__ __launch_bounds__(256) void finalize32_kernel(
    const float* __restrict__ accum, const float* __restrict__ denom,
    float* __restrict__ h, int N)
{
    int t = blockIdx.x * 256 + threadIdx.x;
    if (t >= N * 32) return;
    int i = t >> 5;
    float dnm = fmaxf(denom[i], 1e-9f);
    float v = accum[t] / dnm;
    h[t] = (v > 0.f) ? v : 0.f;
}

// ---- finalize layer 3: out = sigmoid(accum/denom) ----
__global__ __launch_bounds__(256) void finalize3_kernel(
    const float* __restrict__ accum, const float* __restrict__ denom,
    float* __restrict__ out, int N)
{
    int i = blockIdx.x * 256 + threadIdx.x;
    if (i >= N) return;
    float dnm = fmaxf(denom[i], 1e-9f);
    float v = accum[i] / dnm;
    out[i] = 1.f / (1.f + __expf(-v));
}

extern "C" void kernel_launch(void* const* d_in, const int* in_sizes, int n_in,
                              void* d_out, int out_size, void* d_ws, size_t ws_size,
                              hipStream_t stream)
{
    const float* feature = (const float*)d_in[0];
    const int*   src     = (const int*)d_in[1];
    const int*   dst     = (const int*)d_in[2];
    const float* W1      = (const float*)d_in[3];
    const float* a1      = (const float*)d_in[4];
    const float* W2      = (const float*)d_in[5];
    const float* a2      = (const float*)d_in[6];
    const float* W3      = (const float*)d_in[7];
    const float* a3      = (const float*)d_in[8];
    float* out = (float*)d_out;

    const int N = in_sizes[0] / 128;
    const int E = in_sizes[1];

    // ---- workspace layout (floats) ----
    char* p = (char*)d_ws;
    float* zbuf   = (float*)p;  p += (size_t)N * 32 * sizeof(float);
    float* hbuf   = (float*)p;  p += (size_t)N * 32 * sizeof(float);
    float* accum  = (float*)p;  p += (size_t)N * 32 * sizeof(float);
    float* e_ws   = (float*)p;  p += (size_t)E * sizeof(float);
    float* s_src  = (float*)p;  p += (size_t)N * sizeof(float);
    float* s_dst  = (float*)p;  p += (size_t)N * sizeof(float);
    unsigned* mord = (unsigned*)p; p += (size_t)N * sizeof(unsigned);
    float* denom  = (float*)p;  p += (size_t)N * sizeof(float);

    const int nodeBlocks8  = (N + 7) / 8;            // 8 rows per 256-thread block
    const int edgeBlocks   = (E + 255) / 256;
    const int edge32Blocks = (int)(((long long)E * 32 + 255) / 256);
    const int nf32Blocks   = (int)(((long long)N * 32 + 255) / 256);
    const int nodeBlocks   = (N + 255) / 256;

    // ================= layer 1 (128 -> 32, relu) =================
    hipLaunchKernelGGL(gemm1_kernel, dim3(nodeBlocks8), dim3(256), 0, stream,
                       feature, W1, a1, zbuf, s_src, s_dst, N);
    hipMemsetAsync(mord,  0, (size_t)N * 4, stream);
    hipMemsetAsync(denom, 0, (size_t)N * 4, stream);
    hipMemsetAsync(accum, 0, (size_t)N * 32 * 4, stream);
    hipLaunchKernelGGL(edge_max_kernel, dim3(edgeBlocks), dim3(256), 0, stream,
                       src, dst, s_src, s_dst, e_ws, mord, E);
    hipLaunchKernelGGL(edge_agg32_kernel, dim3(edge32Blocks), dim3(256), 0, stream,
                       src, dst, e_ws, mord, zbuf, accum, denom, E);
    hipLaunchKernelGGL(finalize32_kernel, dim3(nf32Blocks), dim3(256), 0, stream,
                       accum, denom, hbuf, N);

    // ================= layer 2 (32 -> 32, relu) =================
    hipLaunchKernelGGL(gemm2_kernel, dim3(nodeBlocks8), dim3(256), 0, stream,
                       hbuf, W2, a2, zbuf, s_src, s_dst, N);
    hipMemsetAsync(mord,  0, (size_t)N * 4, stream);
    hipMemsetAsync(denom, 0, (size_t)N * 4, stream);
    hipMemsetAsync(accum, 0, (size_t)N * 32 * 4, stream);
    hipLaunchKernelGGL(edge_max_kernel, dim3(edgeBlocks), dim3(256), 0, stream,
                       src, dst, s_src, s_dst, e_ws, mord, E);
    hipLaunchKernelGGL(edge_agg32_kernel, dim3(edge32Blocks), dim3(256), 0, stream,
                       src, dst, e_ws, mord, zbuf, accum, denom, E);
    hipLaunchKernelGGL(finalize32_kernel, dim3(nf32Blocks), dim3(256), 0, stream,
                       accum, denom, hbuf, N);

    // ================= layer 3 (32 -> 1, sigmoid) =================
    hipLaunchKernelGGL(gemm3_kernel, dim3(nodeBlocks), dim3(256), 0, stream,
                       hbuf, W3, a3, zbuf, s_src, s_dst, N);  // zbuf[:N] = z3
    hipMemsetAsync(mord,  0, (size_t)N * 4, stream);
    hipMemsetAsync(denom, 0, (size_t)N * 4, stream);
    hipMemsetAsync(accum, 0, (size_t)N * 4, stream);
    hipLaunchKernelGGL(edge_max_kernel, dim3(edgeBlocks), dim3(256), 0, stream,
                       src, dst, s_src, s_dst, e_ws, mord, E);
    hipLaunchKernelGGL(edge_agg1_kernel, dim3(edgeBlocks), dim3(256), 0, stream,
                       src, dst, e_ws, mord, zbuf, accum, denom, E);
    hipLaunchKernelGGL(finalize3_kernel, dim3(nodeBlocks), dim3(256), 0, stream,
                       accum, denom, out, N);
}

// Round 2
// 619.860 us; speedup vs baseline: 1.8435x; 1.8435x over previous
//
#include <hip/hip_runtime.h>
#include <cstdint>
#include <cstddef>

#define NEG_SLOPE 0.01f

// ============================================================================
// GEMM kernels (unchanged from R1 — not hot)
// ============================================================================

// z = h[N,128] @ W[128,32], plus s_src/s_dst logits
__global__ __launch_bounds__(256) void gemm1_kernel(
    const float* __restrict__ h, const float* __restrict__ W,
    const float* __restrict__ a, float* __restrict__ z,
    float* __restrict__ s_src, float* __restrict__ s_dst, int N)
{
    __shared__ float Wl[128 * 32];
    int tid = threadIdx.x;
    for (int i = tid; i < 128 * 32; i += 256) Wl[i] = W[i];
    __syncthreads();

    int row = blockIdx.x * 8 + (tid >> 5);
    int col = tid & 31;
    if (row >= N) return;

    const float* hp = h + (size_t)row * 128;
    float hv[4];
#pragma unroll
    for (int c = 0; c < 4; c++) hv[c] = hp[c * 32 + col];

    float acc = 0.f;
#pragma unroll
    for (int k = 0; k < 128; k++) {
        float hk = __shfl(hv[k >> 5], k & 31, 32);
        acc += hk * Wl[k * 32 + col];
    }
    z[(size_t)row * 32 + col] = acc;

    float ps = acc * a[col];
    float pd = acc * a[32 + col];
#pragma unroll
    for (int off = 16; off > 0; off >>= 1) {
        ps += __shfl_xor(ps, off, 32);
        pd += __shfl_xor(pd, off, 32);
    }
    if (col == 0) { s_src[row] = ps; s_dst[row] = pd; }
}

// z = h[N,32] @ W[32,32], plus logits
__global__ __launch_bounds__(256) void gemm2_kernel(
    const float* __restrict__ h, const float* __restrict__ W,
    const float* __restrict__ a, float* __restrict__ z,
    float* __restrict__ s_src, float* __restrict__ s_dst, int N)
{
    __shared__ float Wl[32 * 32];
    int tid = threadIdx.x;
    for (int i = tid; i < 32 * 32; i += 256) Wl[i] = W[i];
    __syncthreads();

    int row = blockIdx.x * 8 + (tid >> 5);
    int col = tid & 31;
    if (row >= N) return;

    float hv = h[(size_t)row * 32 + col];
    float acc = 0.f;
#pragma unroll
    for (int k = 0; k < 32; k++)
        acc += __shfl(hv, k, 32) * Wl[k * 32 + col];

    z[(size_t)row * 32 + col] = acc;

    float ps = acc * a[col];
    float pd = acc * a[32 + col];
#pragma unroll
    for (int off = 16; off > 0; off >>= 1) {
        ps += __shfl_xor(ps, off, 32);
        pd += __shfl_xor(pd, off, 32);
    }
    if (col == 0) { s_src[row] = ps; s_dst[row] = pd; }
}

// z = h[N,32] @ W[32,1], logits are scalar scales of z
__global__ __launch_bounds__(256) void gemm3_kernel(
    const float* __restrict__ h, const float* __restrict__ W,
    const float* __restrict__ a, float* __restrict__ z,
    float* __restrict__ s_src, float* __restrict__ s_dst, int N)
{
    int i = blockIdx.x * 256 + threadIdx.x;
    if (i >= N) return;
    const float4* hp = (const float4*)(h + (size_t)i * 32);
    const float4* wp = (const float4*)W;
    float acc = 0.f;
#pragma unroll
    for (int c = 0; c < 8; c++) {
        float4 v = hp[c];
        float4 w = wp[c];
        acc += v.x * w.x + v.y * w.y + v.z * w.z + v.w * w.w;
    }
    z[i] = acc;
    s_src[i] = acc * a[0];
    s_dst[i] = acc * a[1];
}

// ============================================================================
// CSR construction (once per call, reused by all 3 layers)
// ============================================================================

__global__ __launch_bounds__(256) void hist_kernel(
    const int* __restrict__ dst, int* __restrict__ deg, int E)
{
    int k = blockIdx.x * 256 + threadIdx.x;
    if (k >= E) return;
    atomicAdd(&deg[dst[k]], 1);
}

// phase 1: per-block (256-wide) inclusive scan + block totals
__global__ __launch_bounds__(256) void scan1_kernel(
    const int* __restrict__ deg, int* __restrict__ incl,
    int* __restrict__ blockSums, int N)
{
    __shared__ int tmp[256];
    int tid = threadIdx.x;
    int i = blockIdx.x * 256 + tid;
    int v = (i < N) ? deg[i] : 0;
    tmp[tid] = v;
    __syncthreads();
#pragma unroll
    for (int off = 1; off < 256; off <<= 1) {
        int t = (tid >= off) ? tmp[tid - off] : 0;
        __syncthreads();
        tmp[tid] += t;
        __syncthreads();
    }
    if (i < N) incl[i] = tmp[tid];
    if (tid == 255) blockSums[blockIdx.x] = tmp[255];
}

// phase 2: single block exclusive-scans blockSums (nb <= 512)
__global__ __launch_bounds__(512) void scan2_kernel(int* __restrict__ blockSums, int nb)
{
    __shared__ int tmp[512];
    int tid = threadIdx.x;
    int v = (tid < nb) ? blockSums[tid] : 0;
    tmp[tid] = v;
    __syncthreads();
#pragma unroll
    for (int off = 1; off < 512; off <<= 1) {
        int t = (tid >= off) ? tmp[tid - off] : 0;
        __syncthreads();
        tmp[tid] += t;
        __syncthreads();
    }
    if (tid < nb) blockSums[tid] = tmp[tid] - v;  // exclusive
}

// phase 3: offsets (exclusive) + cursor copy; offsets[N] = E
__global__ __launch_bounds__(256) void scan3_kernel(
    const int* __restrict__ deg, const int* __restrict__ incl,
    const int* __restrict__ blockSums, int* __restrict__ offsets,
    int* __restrict__ cursor, int N, int E)
{
    int i = blockIdx.x * 256 + threadIdx.x;
    if (i < N) {
        int off = incl[i] - deg[i] + blockSums[i >> 8];
        offsets[i] = off;
        cursor[i]  = off;
    }
    if (i == 0) offsets[N] = E;
}

// scatter: csr_src[cursor[dst]++] = src
__global__ __launch_bounds__(256) void scatter_kernel(
    const int* __restrict__ src, const int* __restrict__ dst,
    int* __restrict__ cursor, int* __restrict__ csr_src, int E)
{
    int k = blockIdx.x * 256 + threadIdx.x;
    if (k >= E) return;
    int pos = atomicAdd(&cursor[dst[k]], 1);
    csr_src[pos] = src[k];
}

// ============================================================================
// CSR aggregation: one 32-lane group per dst node, online softmax over
// in-edges, fused relu. No atomics, each output written exactly once.
// ============================================================================

__global__ __launch_bounds__(256) void agg32_csr_kernel(
    const int* __restrict__ offsets, const int* __restrict__ csr_src,
    const float* __restrict__ s_src, const float* __restrict__ s_dst,
    const float* __restrict__ z, float* __restrict__ h, int N)
{
    int node = blockIdx.x * 8 + (threadIdx.x >> 5);
    int col  = threadIdx.x & 31;
    if (node >= N) return;

    int beg = offsets[node], end = offsets[node + 1];
    float sd = s_dst[node];

    float m = -3.0e38f, l = 0.f, o = 0.f;
    for (int p = beg; p < end; ++p) {
        int s = csr_src[p];                 // broadcast (same addr across group)
        float e = s_src[s] + sd;
        e = (e > 0.f) ? e : NEG_SLOPE * e;
        float zv = z[(size_t)s * 32 + col]; // coalesced 128B gather
        float w;
        if (e > m) {
            float c = __expf(m - e);
            l *= c; o *= c; m = e; w = 1.f;
        } else {
            w = __expf(e - m);
        }
        l += w;
        o += w * zv;
    }
    float v = o / fmaxf(l, 1e-9f);
    h[(size_t)node * 32 + col] = (v > 0.f) ? v : 0.f;  // relu
}

// d_out = 1: one thread per node, serial online softmax, fused sigmoid
__global__ __launch_bounds__(256) void agg1_csr_kernel(
    const int* __restrict__ offsets, const int* __restrict__ csr_src,
    const float* __restrict__ s_src, const float* __restrict__ s_dst,
    const float* __restrict__ z, float* __restrict__ out, int N)
{
    int node = blockIdx.x * 256 + threadIdx.x;
    if (node >= N) return;

    int beg = offsets[node], end = offsets[node + 1];
    float sd = s_dst[node];

    float m = -3.0e38f, l = 0.f, o = 0.f;
    for (int p = beg; p < end; ++p) {
        int s = csr_src[p];
        float e = s_src[s] + sd;
        e = (e > 0.f) ? e : NEG_SLOPE * e;
        float zv = z[s];
        float w;
        if (e > m) {
            float c = __expf(m - e);
            l *= c; o *= c; m = e; w = 1.f;
        } else {
            w = __expf(e - m);
        }
        l += w;
        o += w * zv;
    }
    float v = o / fmaxf(l, 1e-9f);
    out[node] = 1.f / (1.f + __expf(-v));
}

// ============================================================================

extern "C" void kernel_launch(void* const* d_in, const int* in_sizes, int n_in,
                              void* d_out, int out_size, void* d_ws, size_t ws_size,
                              hipStream_t stream)
{
    const float* feature = (const float*)d_in[0];
    const int*   src     = (const int*)d_in[1];
    const int*   dst     = (const int*)d_in[2];
    const float* W1      = (const float*)d_in[3];
    const float* a1      = (const float*)d_in[4];
    const float* W2      = (const float*)d_in[5];
    const float* a2      = (const float*)d_in[6];
    const float* W3      = (const float*)d_in[7];
    const float* a3      = (const float*)d_in[8];
    float* out = (float*)d_out;

    const int N = in_sizes[0] / 128;
    const int E = in_sizes[1];

    // ---- workspace layout ----
    char* p = (char*)d_ws;
    float* zbuf    = (float*)p;  p += (size_t)N * 32 * sizeof(float);
    float* hbuf    = (float*)p;  p += (size_t)N * 32 * sizeof(float);
    float* s_src   = (float*)p;  p += (size_t)N * sizeof(float);
    float* s_dst   = (float*)p;  p += (size_t)N * sizeof(float);
    int*   deg     = (int*)p;    p += (size_t)N * sizeof(int);
    int*   incl    = (int*)p;    p += (size_t)N * sizeof(int);
    int*   offsets = (int*)p;    p += ((size_t)N + 1) * sizeof(int);
    int*   cursor  = (int*)p;    p += (size_t)N * sizeof(int);
    int*   blockSums = (int*)p;  p += 512 * sizeof(int);
    int*   csr_src = (int*)p;    p += (size_t)E * sizeof(int);

    const int nodeBlocks8 = (N + 7) / 8;
    const int nodeBlocks  = (N + 255) / 256;
    const int edgeBlocks  = (E + 255) / 256;
    const int scanBlocks  = (N + 255) / 256;   // = 391 for N=100000 (<= 512)

    // ---- build CSR once ----
    hipMemsetAsync(deg, 0, (size_t)N * sizeof(int), stream);
    hipLaunchKernelGGL(hist_kernel, dim3(edgeBlocks), dim3(256), 0, stream,
                       dst, deg, E);
    hipLaunchKernelGGL(scan1_kernel, dim3(scanBlocks), dim3(256), 0, stream,
                       deg, incl, blockSums, N);
    hipLaunchKernelGGL(scan2_kernel, dim3(1), dim3(512), 0, stream,
                       blockSums, scanBlocks);
    hipLaunchKernelGGL(scan3_kernel, dim3(scanBlocks), dim3(256), 0, stream,
                       deg, incl, blockSums, offsets, cursor, N, E);
    hipLaunchKernelGGL(scatter_kernel, dim3(edgeBlocks), dim3(256), 0, stream,
                       src, dst, cursor, csr_src, E);

    // ---- layer 1 (128 -> 32, relu) ----
    hipLaunchKernelGGL(gemm1_kernel, dim3(nodeBlocks8), dim3(256), 0, stream,
                       feature, W1, a1, zbuf, s_src, s_dst, N);
    hipLaunchKernelGGL(agg32_csr_kernel, dim3(nodeBlocks8), dim3(256), 0, stream,
                       offsets, csr_src, s_src, s_dst, zbuf, hbuf, N);

    // ---- layer 2 (32 -> 32, relu) ----
    hipLaunchKernelGGL(gemm2_kernel, dim3(nodeBlocks8), dim3(256), 0, stream,
                       hbuf, W2, a2, zbuf, s_src, s_dst, N);
    hipLaunchKernelGGL(agg32_csr_kernel, dim3(nodeBlocks8), dim3(256), 0, stream,
                       offsets, csr_src, s_src, s_dst, zbuf, hbuf, N);
    // NOTE: agg32 writes hbuf in-place over the layer-2 input — safe because
    // it reads zbuf (layer-2 z), not hbuf.

    // ---- layer 3 (32 -> 1, sigmoid) ----
    hipLaunchKernelGGL(gemm3_kernel, dim3(nodeBlocks), dim3(256), 0, stream,
                       hbuf, W3, a3, zbuf, s_src, s_dst, N);   // zbuf[:N] = z3
    hipLaunchKernelGGL(agg1_csr_kernel, dim3(nodeBlocks), dim3(256), 0, stream,
                       offsets, csr_src, s_src, s_dst, zbuf, out, N);
}

// Round 3
// 561.150 us; speedup vs baseline: 2.0363x; 1.1046x over previous
//
#include <hip/hip_runtime.h>
#include <cstdint>
#include <cstddef>

#define NEG_SLOPE 0.01f

// ============================================================================
// GEMM kernels
// ============================================================================

// z = h[N,128] @ W[128,32], plus s_src/s_dst logits
__global__ __launch_bounds__(256) void gemm1_kernel(
    const float* __restrict__ h, const float* __restrict__ W,
    const float* __restrict__ a, float* __restrict__ z,
    float* __restrict__ s_src, float* __restrict__ s_dst, int N)
{
    __shared__ float Wl[128 * 32];
    int tid = threadIdx.x;
    for (int i = tid; i < 128 * 32; i += 256) Wl[i] = W[i];
    __syncthreads();

    int row = blockIdx.x * 8 + (tid >> 5);
    int col = tid & 31;
    if (row >= N) return;

    const float* hp = h + (size_t)row * 128;
    float hv[4];
#pragma unroll
    for (int c = 0; c < 4; c++) hv[c] = hp[c * 32 + col];

    float acc = 0.f;
#pragma unroll
    for (int k = 0; k < 128; k++) {
        float hk = __shfl(hv[k >> 5], k & 31, 32);
        acc += hk * Wl[k * 32 + col];
    }
    z[(size_t)row * 32 + col] = acc;

    float ps = acc * a[col];
    float pd = acc * a[32 + col];
#pragma unroll
    for (int off = 16; off > 0; off >>= 1) {
        ps += __shfl_xor(ps, off, 32);
        pd += __shfl_xor(pd, off, 32);
    }
    if (col == 0) { s_src[row] = ps; s_dst[row] = pd; }
}

// z = h[N,32] @ W[32,32], plus logits
__global__ __launch_bounds__(256) void gemm2_kernel(
    const float* __restrict__ h, const float* __restrict__ W,
    const float* __restrict__ a, float* __restrict__ z,
    float* __restrict__ s_src, float* __restrict__ s_dst, int N)
{
    __shared__ float Wl[32 * 32];
    int tid = threadIdx.x;
    for (int i = tid; i < 32 * 32; i += 256) Wl[i] = W[i];
    __syncthreads();

    int row = blockIdx.x * 8 + (tid >> 5);
    int col = tid & 31;
    if (row >= N) return;

    float hv = h[(size_t)row * 32 + col];
    float acc = 0.f;
#pragma unroll
    for (int k = 0; k < 32; k++)
        acc += __shfl(hv, k, 32) * Wl[k * 32 + col];

    z[(size_t)row * 32 + col] = acc;

    float ps = acc * a[col];
    float pd = acc * a[32 + col];
#pragma unroll
    for (int off = 16; off > 0; off >>= 1) {
        ps += __shfl_xor(ps, off, 32);
        pd += __shfl_xor(pd, off, 32);
    }
    if (col == 0) { s_src[row] = ps; s_dst[row] = pd; }
}

// layer 3: zs[i] = {z, z*a0} interleaved (one-line gather in agg1), s_dst sep.
__global__ __launch_bounds__(256) void gemm3_kernel(
    const float* __restrict__ h, const float* __restrict__ W,
    const float* __restrict__ a, float2* __restrict__ zs,
    float* __restrict__ s_dst, int N)
{
    int i = blockIdx.x * 256 + threadIdx.x;
    if (i >= N) return;
    const float4* hp = (const float4*)(h + (size_t)i * 32);
    const float4* wp = (const float4*)W;
    float acc = 0.f;
#pragma unroll
    for (int c = 0; c < 8; c++) {
        float4 v = hp[c];
        float4 w = wp[c];
        acc += v.x * w.x + v.y * w.y + v.z * w.z + v.w * w.w;
    }
    zs[i] = make_float2(acc, acc * a[0]);
    s_dst[i] = acc * a[1];
}

// ============================================================================
// CSR construction via per-dst linked list (no scattered-write amplification)
// ============================================================================

// ll[k] = {prev head (next ptr), src[k]}; head[d] updated by atomicExch.
__global__ __launch_bounds__(256) void build_ll_kernel(
    const int* __restrict__ src, const int* __restrict__ dst,
    int* __restrict__ head, int2* __restrict__ ll, int E)
{
    int k = blockIdx.x * 256 + threadIdx.x;
    if (k >= E) return;
    int d = dst[k];
    int s = src[k];
    int old = atomicExch(&head[d], k);
    ll[k] = make_int2(old, s);   // coalesced 8B store
}

// thread per node: walk chain, count degree
__global__ __launch_bounds__(256) void walk_count_kernel(
    const int* __restrict__ head, const int2* __restrict__ ll,
    int* __restrict__ deg, int N)
{
    int i = blockIdx.x * 256 + threadIdx.x;
    if (i >= N) return;
    int c = 0;
    int e = head[i];
    while (e >= 0) { c++; e = ll[e].x; }
    deg[i] = c;
}

// phase 1: per-block inclusive scan of deg -> offsets (inclusive), block totals
__global__ __launch_bounds__(256) void scan1_kernel(
    const int* __restrict__ deg, int* __restrict__ offsets,
    int* __restrict__ blockSums, int N)
{
    __shared__ int tmp[256];
    int tid = threadIdx.x;
    int i = blockIdx.x * 256 + tid;
    int v = (i < N) ? deg[i] : 0;
    tmp[tid] = v;
    __syncthreads();
#pragma unroll
    for (int off = 1; off < 256; off <<= 1) {
        int t = (tid >= off) ? tmp[tid - off] : 0;
        __syncthreads();
        tmp[tid] += t;
        __syncthreads();
    }
    if (i < N) offsets[i] = tmp[tid];
    if (tid == 255) blockSums[blockIdx.x] = tmp[255];
}

// phase 2: single block exclusive-scans blockSums (nb <= 512)
__global__ __launch_bounds__(512) void scan2_kernel(int* __restrict__ blockSums, int nb)
{
    __shared__ int tmp[512];
    int tid = threadIdx.x;
    int v = (tid < nb) ? blockSums[tid] : 0;
    tmp[tid] = v;
    __syncthreads();
#pragma unroll
    for (int off = 1; off < 512; off <<= 1) {
        int t = (tid >= off) ? tmp[tid - off] : 0;
        __syncthreads();
        tmp[tid] += t;
        __syncthreads();
    }
    if (tid < nb) blockSums[tid] = tmp[tid] - v;  // exclusive
}

// phase 3: offsets inclusive -> exclusive (in place); offsets[N] = E
__global__ __launch_bounds__(256) void scan3_kernel(
    const int* __restrict__ deg, const int* __restrict__ blockSums,
    int* __restrict__ offsets, int N, int E)
{
    int i = blockIdx.x * 256 + threadIdx.x;
    if (i < N) {
        offsets[i] = offsets[i] - deg[i] + blockSums[i >> 8];
    }
    if (i == 0) offsets[N] = E;
}

// thread per node: walk chain, write src ids sequentially into csr_src
__global__ __launch_bounds__(256) void walk_write_kernel(
    const int* __restrict__ head, const int2* __restrict__ ll,
    const int* __restrict__ offsets, int* __restrict__ csr_src, int N)
{
    int i = blockIdx.x * 256 + threadIdx.x;
    if (i >= N) return;
    int p = offsets[i];
    int e = head[i];
    while (e >= 0) {
        int2 v = ll[e];
        csr_src[p++] = v.y;   // sequential per node
        e = v.x;
    }
}

// ============================================================================
// CSR aggregation: online softmax, no atomics, fused activation
// ============================================================================

__global__ __launch_bounds__(256) void agg32_csr_kernel(
    const int* __restrict__ offsets, const int* __restrict__ csr_src,
    const float* __restrict__ s_src, const float* __restrict__ s_dst,
    const float* __restrict__ z, float* __restrict__ h, int N)
{
    int node = blockIdx.x * 8 + (threadIdx.x >> 5);
    int col  = threadIdx.x & 31;
    if (node >= N) return;

    int beg = offsets[node], end = offsets[node + 1];
    float sd = s_dst[node];

    float m = -3.0e38f, l = 0.f, o = 0.f;
    for (int p = beg; p < end; ++p) {
        int s = csr_src[p];                 // broadcast
        float e = s_src[s] + sd;
        e = (e > 0.f) ? e : NEG_SLOPE * e;
        float zv = z[(size_t)s * 32 + col]; // coalesced 128B gather
        float w;
        if (e > m) {
            float c = __expf(m - e);
            l *= c; o *= c; m = e; w = 1.f;
        } else {
            w = __expf(e - m);
        }
        l += w;
        o += w * zv;
    }
    float v = o / fmaxf(l, 1e-9f);
    h[(size_t)node * 32 + col] = (v > 0.f) ? v : 0.f;  // relu
}

// d_out = 1: thread per node; zs = {z, s_src} single-line gather; sigmoid
__global__ __launch_bounds__(256) void agg1_csr_kernel(
    const int* __restrict__ offsets, const int* __restrict__ csr_src,
    const float2* __restrict__ zs, const float* __restrict__ s_dst,
    float* __restrict__ out, int N)
{
    int node = blockIdx.x * 256 + threadIdx.x;
    if (node >= N) return;

    int beg = offsets[node], end = offsets[node + 1];
    float sd = s_dst[node];

    float m = -3.0e38f, l = 0.f, o = 0.f;
    for (int p = beg; p < end; ++p) {
        int s = csr_src[p];
        float2 v2 = zs[s];                  // one 8B gather, one line
        float e = v2.y + sd;
        e = (e > 0.f) ? e : NEG_SLOPE * e;
        float w;
        if (e > m) {
            float c = __expf(m - e);
            l *= c; o *= c; m = e; w = 1.f;
        } else {
            w = __expf(e - m);
        }
        l += w;
        o += w * v2.x;
    }
    float v = o / fmaxf(l, 1e-9f);
    out[node] = 1.f / (1.f + __expf(-v));
}

// ============================================================================

extern "C" void kernel_launch(void* const* d_in, const int* in_sizes, int n_in,
                              void* d_out, int out_size, void* d_ws, size_t ws_size,
                              hipStream_t stream)
{
    const float* feature = (const float*)d_in[0];
    const int*   src     = (const int*)d_in[1];
    const int*   dst     = (const int*)d_in[2];
    const float* W1      = (const float*)d_in[3];
    const float* a1      = (const float*)d_in[4];
    const float* W2      = (const float*)d_in[5];
    const float* a2      = (const float*)d_in[6];
    const float* W3      = (const float*)d_in[7];
    const float* a3      = (const float*)d_in[8];
    float* out = (float*)d_out;

    const int N = in_sizes[0] / 128;
    const int E = in_sizes[1];

    // ---- workspace layout ----
    char* p = (char*)d_ws;
    float* zbuf    = (float*)p;  p += (size_t)N * 32 * sizeof(float);
    float* hbuf    = (float*)p;  p += (size_t)N * 32 * sizeof(float);
    float* s_src   = (float*)p;  p += (size_t)N * sizeof(float);
    float* s_dst   = (float*)p;  p += (size_t)N * sizeof(float);
    int*   head    = (int*)p;    p += (size_t)N * sizeof(int);
    int*   deg     = (int*)p;    p += (size_t)N * sizeof(int);
    int*   offsets = (int*)p;    p += ((size_t)N + 1) * sizeof(int);
    int*   blockSums = (int*)p;  p += 512 * sizeof(int);
    int2*  ll      = (int2*)p;   p += (size_t)E * sizeof(int2);
    int*   csr_src = (int*)p;    p += (size_t)E * sizeof(int);

    const int nodeBlocks8 = (N + 7) / 8;
    const int nodeBlocks  = (N + 255) / 256;
    const int edgeBlocks  = (E + 255) / 256;
    const int scanBlocks  = (N + 255) / 256;   // 391 for N=100000 (<=512)

    // ---- build CSR once via linked list ----
    hipMemsetAsync(head, 0xFF, (size_t)N * sizeof(int), stream);   // head = -1
    hipLaunchKernelGGL(build_ll_kernel, dim3(edgeBlocks), dim3(256), 0, stream,
                       src, dst, head, ll, E);
    hipLaunchKernelGGL(walk_count_kernel, dim3(nodeBlocks), dim3(256), 0, stream,
                       head, ll, deg, N);
    hipLaunchKernelGGL(scan1_kernel, dim3(scanBlocks), dim3(256), 0, stream,
                       deg, offsets, blockSums, N);
    hipLaunchKernelGGL(scan2_kernel, dim3(1), dim3(512), 0, stream,
                       blockSums, scanBlocks);
    hipLaunchKernelGGL(scan3_kernel, dim3(scanBlocks), dim3(256), 0, stream,
                       deg, blockSums, offsets, N, E);
    hipLaunchKernelGGL(walk_write_kernel, dim3(nodeBlocks), dim3(256), 0, stream,
                       head, ll, offsets, csr_src, N);

    // ---- layer 1 (128 -> 32, relu) ----
    hipLaunchKernelGGL(gemm1_kernel, dim3(nodeBlocks8), dim3(256), 0, stream,
                       feature, W1, a1, zbuf, s_src, s_dst, N);
    hipLaunchKernelGGL(agg32_csr_kernel, dim3(nodeBlocks8), dim3(256), 0, stream,
                       offsets, csr_src, s_src, s_dst, zbuf, hbuf, N);

    // ---- layer 2 (32 -> 32, relu) ----
    hipLaunchKernelGGL(gemm2_kernel, dim3(nodeBlocks8), dim3(256), 0, stream,
                       hbuf, W2, a2, zbuf, s_src, s_dst, N);
    hipLaunchKernelGGL(agg32_csr_kernel, dim3(nodeBlocks8), dim3(256), 0, stream,
                       offsets, csr_src, s_src, s_dst, zbuf, hbuf, N);

    // ---- layer 3 (32 -> 1, sigmoid) ----
    // zs (float2[N]) reuses zbuf (needs 2N floats <= 32N available)
    float2* zs = (float2*)zbuf;
    hipLaunchKernelGGL(gemm3_kernel, dim3(nodeBlocks), dim3(256), 0, stream,
                       hbuf, W3, a3, zs, s_dst, N);
    hipLaunchKernelGGL(agg1_csr_kernel, dim3(nodeBlocks), dim3(256), 0, stream,
                       offsets, csr_src, zs, s_dst, out, N);
}

// Round 4
// 487.699 us; speedup vs baseline: 2.3430x; 1.1506x over previous
//
#include <hip/hip_runtime.h>
#include <cstdint>
#include <cstddef>

#define NEG_SLOPE 0.01f

// ============================================================================
// GEMM kernels — register-blocked 4x4 micro-tiles, b128 LDS reads, no shfl
// in the hot loop. LDS instrs per FMA cut ~8x vs shuffle version.
// ============================================================================

// z = h[N,128] @ W[128,32] + logits. Block = 128 threads (2 waves), 64 rows.
// Lane micro-tile: 4 rows x 4 cols. h row stride 140 floats (2-way bank = free).
__global__ __launch_bounds__(128) void gemm1_kernel(
    const float* __restrict__ h, const float* __restrict__ W,
    const float* __restrict__ a, float* __restrict__ z,
    float* __restrict__ s_src, float* __restrict__ s_dst, int N)
{
    __shared__ float Hl[64 * 140];   // 35840 B
    __shared__ float Wl[128 * 32];   // 16384 B
    int tid = threadIdx.x;
    int rowBase = blockIdx.x * 64;

    // stage W: 1024 float4
    {
        const float4* W4 = (const float4*)W;
        float4* Wl4 = (float4*)Wl;
        for (int i = tid; i < 1024; i += 128) Wl4[i] = W4[i];
    }
    // stage h: 64 rows x 32 float4, padded stride 140 floats
    {
        const float4* h4 = (const float4*)h;
        for (int i = tid; i < 64 * 32; i += 128) {
            int r = i >> 5, kq = i & 31;
            float4 v = (rowBase + r < N) ? h4[(size_t)(rowBase + r) * 32 + kq]
                                         : make_float4(0.f, 0.f, 0.f, 0.f);
            *(float4*)&Hl[r * 140 + kq * 4] = v;
        }
    }
    __syncthreads();

    int wv   = tid >> 6;         // wave 0..1
    int lane = tid & 63;
    int g    = lane >> 3;        // row-group 0..7
    int l8   = lane & 7;         // col-group 0..7
    int r0   = wv * 32 + g * 4;  // local row base (4 rows)
    int col4 = l8 * 4;

    float acc[4][4];
#pragma unroll
    for (int i = 0; i < 4; i++)
#pragma unroll
        for (int c = 0; c < 4; c++) acc[i][c] = 0.f;

    const float4* H4  = (const float4*)Hl;  // row stride 35 float4
    const float4* Wl4 = (const float4*)Wl;  // 8 float4 per k

#pragma unroll 2
    for (int kq = 0; kq < 32; kq++) {
        float4 w0 = Wl4[(kq * 4 + 0) * 8 + l8];
        float4 w1 = Wl4[(kq * 4 + 1) * 8 + l8];
        float4 w2 = Wl4[(kq * 4 + 2) * 8 + l8];
        float4 w3 = Wl4[(kq * 4 + 3) * 8 + l8];
#pragma unroll
        for (int i = 0; i < 4; i++) {
            float4 hv = H4[(r0 + i) * 35 + kq];
            acc[i][0] += hv.x * w0.x; acc[i][1] += hv.x * w0.y;
            acc[i][2] += hv.x * w0.z; acc[i][3] += hv.x * w0.w;
            acc[i][0] += hv.y * w1.x; acc[i][1] += hv.y * w1.y;
            acc[i][2] += hv.y * w1.z; acc[i][3] += hv.y * w1.w;
            acc[i][0] += hv.z * w2.x; acc[i][1] += hv.z * w2.y;
            acc[i][2] += hv.z * w2.z; acc[i][3] += hv.z * w2.w;
            acc[i][0] += hv.w * w3.x; acc[i][1] += hv.w * w3.y;
            acc[i][2] += hv.w * w3.z; acc[i][3] += hv.w * w3.w;
        }
    }

    float4 alo = ((const float4*)a)[l8];       // a[col4..+3]
    float4 ahi = ((const float4*)a)[8 + l8];   // a[32+col4..+3]
#pragma unroll
    for (int i = 0; i < 4; i++) {
        int row = rowBase + r0 + i;
        if (row < N) {   // uniform across the 8-lane shuffle cluster
            float4 zv = make_float4(acc[i][0], acc[i][1], acc[i][2], acc[i][3]);
            *(float4*)&z[(size_t)row * 32 + col4] = zv;
            float ps = zv.x * alo.x + zv.y * alo.y + zv.z * alo.z + zv.w * alo.w;
            float pd = zv.x * ahi.x + zv.y * ahi.y + zv.z * ahi.z + zv.w * ahi.w;
            ps += __shfl_xor(ps, 1, 64); ps += __shfl_xor(ps, 2, 64); ps += __shfl_xor(ps, 4, 64);
            pd += __shfl_xor(pd, 1, 64); pd += __shfl_xor(pd, 2, 64); pd += __shfl_xor(pd, 4, 64);
            if (l8 == 0) { s_src[row] = ps; s_dst[row] = pd; }
        }
    }
}

// z = h[N,32] @ W[32,32] + logits. Same structure, K=32, h stride 44.
__global__ __launch_bounds__(128) void gemm2_kernel(
    const float* __restrict__ h, const float* __restrict__ W,
    const float* __restrict__ a, float* __restrict__ z,
    float* __restrict__ s_src, float* __restrict__ s_dst, int N)
{
    __shared__ float Hl[64 * 44];    // 11264 B
    __shared__ float Wl[32 * 32];    // 4096 B
    int tid = threadIdx.x;
    int rowBase = blockIdx.x * 64;

    {
        const float4* W4 = (const float4*)W;
        float4* Wl4 = (float4*)Wl;
        for (int i = tid; i < 256; i += 128) Wl4[i] = W4[i];
    }
    {
        const float4* h4 = (const float4*)h;
        for (int i = tid; i < 64 * 8; i += 128) {
            int r = i >> 3, kq = i & 7;
            float4 v = (rowBase + r < N) ? h4[(size_t)(rowBase + r) * 8 + kq]
                                         : make_float4(0.f, 0.f, 0.f, 0.f);
            *(float4*)&Hl[r * 44 + kq * 4] = v;
        }
    }
    __syncthreads();

    int wv   = tid >> 6;
    int lane = tid & 63;
    int g    = lane >> 3;
    int l8   = lane & 7;
    int r0   = wv * 32 + g * 4;
    int col4 = l8 * 4;

    float acc[4][4];
#pragma unroll
    for (int i = 0; i < 4; i++)
#pragma unroll
        for (int c = 0; c < 4; c++) acc[i][c] = 0.f;

    const float4* H4  = (const float4*)Hl;  // row stride 11 float4
    const float4* Wl4 = (const float4*)Wl;

#pragma unroll
    for (int kq = 0; kq < 8; kq++) {
        float4 w0 = Wl4[(kq * 4 + 0) * 8 + l8];
        float4 w1 = Wl4[(kq * 4 + 1) * 8 + l8];
        float4 w2 = Wl4[(kq * 4 + 2) * 8 + l8];
        float4 w3 = Wl4[(kq * 4 + 3) * 8 + l8];
#pragma unroll
        for (int i = 0; i < 4; i++) {
            float4 hv = H4[(r0 + i) * 11 + kq];
            acc[i][0] += hv.x * w0.x; acc[i][1] += hv.x * w0.y;
            acc[i][2] += hv.x * w0.z; acc[i][3] += hv.x * w0.w;
            acc[i][0] += hv.y * w1.x; acc[i][1] += hv.y * w1.y;
            acc[i][2] += hv.y * w1.z; acc[i][3] += hv.y * w1.w;
            acc[i][0] += hv.z * w2.x; acc[i][1] += hv.z * w2.y;
            acc[i][2] += hv.z * w2.z; acc[i][3] += hv.z * w2.w;
            acc[i][0] += hv.w * w3.x; acc[i][1] += hv.w * w3.y;
            acc[i][2] += hv.w * w3.z; acc[i][3] += hv.w * w3.w;
        }
    }

    float4 alo = ((const float4*)a)[l8];
    float4 ahi = ((const float4*)a)[8 + l8];
#pragma unroll
    for (int i = 0; i < 4; i++) {
        int row = rowBase + r0 + i;
        if (row < N) {
            float4 zv = make_float4(acc[i][0], acc[i][1], acc[i][2], acc[i][3]);
            *(float4*)&z[(size_t)row * 32 + col4] = zv;
            float ps = zv.x * alo.x + zv.y * alo.y + zv.z * alo.z + zv.w * alo.w;
            float pd = zv.x * ahi.x + zv.y * ahi.y + zv.z * ahi.z + zv.w * ahi.w;
            ps += __shfl_xor(ps, 1, 64); ps += __shfl_xor(ps, 2, 64); ps += __shfl_xor(ps, 4, 64);
            pd += __shfl_xor(pd, 1, 64); pd += __shfl_xor(pd, 2, 64); pd += __shfl_xor(pd, 4, 64);
            if (l8 == 0) { s_src[row] = ps; s_dst[row] = pd; }
        }
    }
}

// layer 3: zs[i] = {z, z*a0} interleaved (one-line gather in agg1), s_dst sep.
__global__ __launch_bounds__(256) void gemm3_kernel(
    const float* __restrict__ h, const float* __restrict__ W,
    const float* __restrict__ a, float2* __restrict__ zs,
    float* __restrict__ s_dst, int N)
{
    int i = blockIdx.x * 256 + threadIdx.x;
    if (i >= N) return;
    const float4* hp = (const float4*)(h + (size_t)i * 32);
    const float4* wp = (const float4*)W;
    float acc = 0.f;
#pragma unroll
    for (int c = 0; c < 8; c++) {
        float4 v = hp[c];
        float4 w = wp[c];
        acc += v.x * w.x + v.y * w.y + v.z * w.z + v.w * w.w;
    }
    zs[i] = make_float2(acc, acc * a[0]);
    s_dst[i] = acc * a[1];
}

// ============================================================================
// CSR construction via per-dst linked list
// ============================================================================

__global__ __launch_bounds__(256) void build_ll_kernel(
    const int* __restrict__ src, const int* __restrict__ dst,
    int* __restrict__ head, int2* __restrict__ ll, int E)
{
    int k = blockIdx.x * 256 + threadIdx.x;
    if (k >= E) return;
    int d = dst[k];
    int s = src[k];
    int old = atomicExch(&head[d], k);
    ll[k] = make_int2(old, s);
}

__global__ __launch_bounds__(256) void walk_count_kernel(
    const int* __restrict__ head, const int2* __restrict__ ll,
    int* __restrict__ deg, int N)
{
    int i = blockIdx.x * 256 + threadIdx.x;
    if (i >= N) return;
    int c = 0;
    int e = head[i];
    while (e >= 0) { c++; e = ll[e].x; }
    deg[i] = c;
}

__global__ __launch_bounds__(256) void scan1_kernel(
    const int* __restrict__ deg, int* __restrict__ offsets,
    int* __restrict__ blockSums, int N)
{
    __shared__ int tmp[256];
    int tid = threadIdx.x;
    int i = blockIdx.x * 256 + tid;
    int v = (i < N) ? deg[i] : 0;
    tmp[tid] = v;
    __syncthreads();
#pragma unroll
    for (int off = 1; off < 256; off <<= 1) {
        int t = (tid >= off) ? tmp[tid - off] : 0;
        __syncthreads();
        tmp[tid] += t;
        __syncthreads();
    }
    if (i < N) offsets[i] = tmp[tid];
    if (tid == 255) blockSums[blockIdx.x] = tmp[255];
}

__global__ __launch_bounds__(512) void scan2_kernel(int* __restrict__ blockSums, int nb)
{
    __shared__ int tmp[512];
    int tid = threadIdx.x;
    int v = (tid < nb) ? blockSums[tid] : 0;
    tmp[tid] = v;
    __syncthreads();
#pragma unroll
    for (int off = 1; off < 512; off <<= 1) {
        int t = (tid >= off) ? tmp[tid - off] : 0;
        __syncthreads();
        tmp[tid] += t;
        __syncthreads();
    }
    if (tid < nb) blockSums[tid] = tmp[tid] - v;
}

__global__ __launch_bounds__(256) void scan3_kernel(
    const int* __restrict__ deg, const int* __restrict__ blockSums,
    int* __restrict__ offsets, int N, int E)
{
    int i = blockIdx.x * 256 + threadIdx.x;
    if (i < N) {
        offsets[i] = offsets[i] - deg[i] + blockSums[i >> 8];
    }
    if (i == 0) offsets[N] = E;
}

__global__ __launch_bounds__(256) void walk_write_kernel(
    const int* __restrict__ head, const int2* __restrict__ ll,
    const int* __restrict__ offsets, int* __restrict__ csr_src, int N)
{
    int i = blockIdx.x * 256 + threadIdx.x;
    if (i >= N) return;
    int p = offsets[i];
    int e = head[i];
    while (e >= 0) {
        int2 v = ll[e];
        csr_src[p++] = v.y;
        e = v.x;
    }
}

// ============================================================================
// CSR aggregation: online softmax, no atomics, fused activation
// ============================================================================

__global__ __launch_bounds__(256) void agg32_csr_kernel(
    const int* __restrict__ offsets, const int* __restrict__ csr_src,
    const float* __restrict__ s_src, const float* __restrict__ s_dst,
    const float* __restrict__ z, float* __restrict__ h, int N)
{
    int node = blockIdx.x * 8 + (threadIdx.x >> 5);
    int col  = threadIdx.x & 31;
    if (node >= N) return;

    int beg = offsets[node], end = offsets[node + 1];
    float sd = s_dst[node];

    float m = -3.0e38f, l = 0.f, o = 0.f;
    for (int p = beg; p < end; ++p) {
        int s = csr_src[p];
        float e = s_src[s] + sd;
        e = (e > 0.f) ? e : NEG_SLOPE * e;
        float zv = z[(size_t)s * 32 + col];
        float w;
        if (e > m) {
            float c = __expf(m - e);
            l *= c; o *= c; m = e; w = 1.f;
        } else {
            w = __expf(e - m);
        }
        l += w;
        o += w * zv;
    }
    float v = o / fmaxf(l, 1e-9f);
    h[(size_t)node * 32 + col] = (v > 0.f) ? v : 0.f;
}

__global__ __launch_bounds__(256) void agg1_csr_kernel(
    const int* __restrict__ offsets, const int* __restrict__ csr_src,
    const float2* __restrict__ zs, const float* __restrict__ s_dst,
    float* __restrict__ out, int N)
{
    int node = blockIdx.x * 256 + threadIdx.x;
    if (node >= N) return;

    int beg = offsets[node], end = offsets[node + 1];
    float sd = s_dst[node];

    float m = -3.0e38f, l = 0.f, o = 0.f;
    for (int p = beg; p < end; ++p) {
        int s = csr_src[p];
        float2 v2 = zs[s];
        float e = v2.y + sd;
        e = (e > 0.f) ? e : NEG_SLOPE * e;
        float w;
        if (e > m) {
            float c = __expf(m - e);
            l *= c; o *= c; m = e; w = 1.f;
        } else {
            w = __expf(e - m);
        }
        l += w;
        o += w * v2.x;
    }
    float v = o / fmaxf(l, 1e-9f);
    out[node] = 1.f / (1.f + __expf(-v));
}

// ============================================================================

extern "C" void kernel_launch(void* const* d_in, const int* in_sizes, int n_in,
                              void* d_out, int out_size, void* d_ws, size_t ws_size,
                              hipStream_t stream)
{
    const float* feature = (const float*)d_in[0];
    const int*   src     = (const int*)d_in[1];
    const int*   dst     = (const int*)d_in[2];
    const float* W1      = (const float*)d_in[3];
    const float* a1      = (const float*)d_in[4];
    const float* W2      = (const float*)d_in[5];
    const float* a2      = (const float*)d_in[6];
    const float* W3      = (const float*)d_in[7];
    const float* a3      = (const float*)d_in[8];
    float* out = (float*)d_out;

    const int N = in_sizes[0] / 128;
    const int E = in_sizes[1];

    // ---- workspace layout ----
    char* p = (char*)d_ws;
    float* zbuf    = (float*)p;  p += (size_t)N * 32 * sizeof(float);
    float* hbuf    = (float*)p;  p += (size_t)N * 32 * sizeof(float);
    float* s_src   = (float*)p;  p += (size_t)N * sizeof(float);
    float* s_dst   = (float*)p;  p += (size_t)N * sizeof(float);
    int*   head    = (int*)p;    p += (size_t)N * sizeof(int);
    int*   deg     = (int*)p;    p += (size_t)N * sizeof(int);
    int*   offsets = (int*)p;    p += ((size_t)N + 1) * sizeof(int);
    int*   blockSums = (int*)p;  p += 512 * sizeof(int);
    int2*  ll      = (int2*)p;   p += (size_t)E * sizeof(int2);
    int*   csr_src = (int*)p;    p += (size_t)E * sizeof(int);

    const int nodeBlocks8  = (N + 7) / 8;
    const int nodeBlocks   = (N + 255) / 256;
    const int edgeBlocks   = (E + 255) / 256;
    const int scanBlocks   = (N + 255) / 256;   // 391 for N=100000 (<=512)
    const int gemmBlocks64 = (N + 63) / 64;     // 64 rows per 128-thread block

    // ---- build CSR once via linked list ----
    hipMemsetAsync(head, 0xFF, (size_t)N * sizeof(int), stream);   // head = -1
    hipLaunchKernelGGL(build_ll_kernel, dim3(edgeBlocks), dim3(256), 0, stream,
                       src, dst, head, ll, E);
    hipLaunchKernelGGL(walk_count_kernel, dim3(nodeBlocks), dim3(256), 0, stream,
                       head, ll, deg, N);
    hipLaunchKernelGGL(scan1_kernel, dim3(scanBlocks), dim3(256), 0, stream,
                       deg, offsets, blockSums, N);
    hipLaunchKernelGGL(scan2_kernel, dim3(1), dim3(512), 0, stream,
                       blockSums, scanBlocks);
    hipLaunchKernelGGL(scan3_kernel, dim3(scanBlocks), dim3(256), 0, stream,
                       deg, blockSums, offsets, N, E);
    hipLaunchKernelGGL(walk_write_kernel, dim3(nodeBlocks), dim3(256), 0, stream,
                       head, ll, offsets, csr_src, N);

    // ---- layer 1 (128 -> 32, relu) ----
    hipLaunchKernelGGL(gemm1_kernel, dim3(gemmBlocks64), dim3(128), 0, stream,
                       feature, W1, a1, zbuf, s_src, s_dst, N);
    hipLaunchKernelGGL(agg32_csr_kernel, dim3(nodeBlocks8), dim3(256), 0, stream,
                       offsets, csr_src, s_src, s_dst, zbuf, hbuf, N);

    // ---- layer 2 (32 -> 32, relu) ----
    hipLaunchKernelGGL(gemm2_kernel, dim3(gemmBlocks64), dim3(128), 0, stream,
                       hbuf, W2, a2, zbuf, s_src, s_dst, N);
    hipLaunchKernelGGL(agg32_csr_kernel, dim3(nodeBlocks8), dim3(256), 0, stream,
                       offsets, csr_src, s_src, s_dst, zbuf, hbuf, N);

    // ---- layer 3 (32 -> 1, sigmoid) ----
    float2* zs = (float2*)zbuf;
    hipLaunchKernelGGL(gemm3_kernel, dim3(nodeBlocks), dim3(256), 0, stream,
                       hbuf, W3, a3, zs, s_dst, N);
    hipLaunchKernelGGL(agg1_csr_kernel, dim3(nodeBlocks), dim3(256), 0, stream,
                       offsets, csr_src, zs, s_dst, out, N);
}

// Round 5
// 478.529 us; speedup vs baseline: 2.3879x; 1.0192x over previous
//
#include <hip/hip_runtime.h>
#include <cstdint>
#include <cstddef>

#define NEG_SLOPE 0.01f

// ============================================================================
// GEMM kernels — register-blocked 4x4 micro-tiles, b128 LDS reads
// ============================================================================

// z = h[N,128] @ W[128,32] + logits. Block = 128 threads (2 waves), 64 rows.
__global__ __launch_bounds__(128) void gemm1_kernel(
    const float* __restrict__ h, const float* __restrict__ W,
    const float* __restrict__ a, float* __restrict__ z,
    float* __restrict__ s_src, float* __restrict__ s_dst, int N)
{
    __shared__ float Hl[64 * 140];   // 35840 B
    __shared__ float Wl[128 * 32];   // 16384 B
    int tid = threadIdx.x;
    int rowBase = blockIdx.x * 64;

    {
        const float4* W4 = (const float4*)W;
        float4* Wl4 = (float4*)Wl;
        for (int i = tid; i < 1024; i += 128) Wl4[i] = W4[i];
    }
    {
        const float4* h4 = (const float4*)h;
        for (int i = tid; i < 64 * 32; i += 128) {
            int r = i >> 5, kq = i & 31;
            float4 v = (rowBase + r < N) ? h4[(size_t)(rowBase + r) * 32 + kq]
                                         : make_float4(0.f, 0.f, 0.f, 0.f);
            *(float4*)&Hl[r * 140 + kq * 4] = v;
        }
    }
    __syncthreads();

    int wv   = tid >> 6;
    int lane = tid & 63;
    int g    = lane >> 3;
    int l8   = lane & 7;
    int r0   = wv * 32 + g * 4;
    int col4 = l8 * 4;

    float acc[4][4];
#pragma unroll
    for (int i = 0; i < 4; i++)
#pragma unroll
        for (int c = 0; c < 4; c++) acc[i][c] = 0.f;

    const float4* H4  = (const float4*)Hl;  // row stride 35 float4
    const float4* Wl4 = (const float4*)Wl;

#pragma unroll 2
    for (int kq = 0; kq < 32; kq++) {
        float4 w0 = Wl4[(kq * 4 + 0) * 8 + l8];
        float4 w1 = Wl4[(kq * 4 + 1) * 8 + l8];
        float4 w2 = Wl4[(kq * 4 + 2) * 8 + l8];
        float4 w3 = Wl4[(kq * 4 + 3) * 8 + l8];
#pragma unroll
        for (int i = 0; i < 4; i++) {
            float4 hv = H4[(r0 + i) * 35 + kq];
            acc[i][0] += hv.x * w0.x; acc[i][1] += hv.x * w0.y;
            acc[i][2] += hv.x * w0.z; acc[i][3] += hv.x * w0.w;
            acc[i][0] += hv.y * w1.x; acc[i][1] += hv.y * w1.y;
            acc[i][2] += hv.y * w1.z; acc[i][3] += hv.y * w1.w;
            acc[i][0] += hv.z * w2.x; acc[i][1] += hv.z * w2.y;
            acc[i][2] += hv.z * w2.z; acc[i][3] += hv.z * w2.w;
            acc[i][0] += hv.w * w3.x; acc[i][1] += hv.w * w3.y;
            acc[i][2] += hv.w * w3.z; acc[i][3] += hv.w * w3.w;
        }
    }

    float4 alo = ((const float4*)a)[l8];
    float4 ahi = ((const float4*)a)[8 + l8];
#pragma unroll
    for (int i = 0; i < 4; i++) {
        int row = rowBase + r0 + i;
        if (row < N) {
            float4 zv = make_float4(acc[i][0], acc[i][1], acc[i][2], acc[i][3]);
            *(float4*)&z[(size_t)row * 32 + col4] = zv;
            float ps = zv.x * alo.x + zv.y * alo.y + zv.z * alo.z + zv.w * alo.w;
            float pd = zv.x * ahi.x + zv.y * ahi.y + zv.z * ahi.z + zv.w * ahi.w;
            ps += __shfl_xor(ps, 1, 64); ps += __shfl_xor(ps, 2, 64); ps += __shfl_xor(ps, 4, 64);
            pd += __shfl_xor(pd, 1, 64); pd += __shfl_xor(pd, 2, 64); pd += __shfl_xor(pd, 4, 64);
            if (l8 == 0) { s_src[row] = ps; s_dst[row] = pd; }
        }
    }
}

// z = h[N,32] @ W[32,32] + logits. Same structure, K=32.
__global__ __launch_bounds__(128) void gemm2_kernel(
    const float* __restrict__ h, const float* __restrict__ W,
    const float* __restrict__ a, float* __restrict__ z,
    float* __restrict__ s_src, float* __restrict__ s_dst, int N)
{
    __shared__ float Hl[64 * 44];
    __shared__ float Wl[32 * 32];
    int tid = threadIdx.x;
    int rowBase = blockIdx.x * 64;

    {
        const float4* W4 = (const float4*)W;
        float4* Wl4 = (float4*)Wl;
        for (int i = tid; i < 256; i += 128) Wl4[i] = W4[i];
    }
    {
        const float4* h4 = (const float4*)h;
        for (int i = tid; i < 64 * 8; i += 128) {
            int r = i >> 3, kq = i & 7;
            float4 v = (rowBase + r < N) ? h4[(size_t)(rowBase + r) * 8 + kq]
                                         : make_float4(0.f, 0.f, 0.f, 0.f);
            *(float4*)&Hl[r * 44 + kq * 4] = v;
        }
    }
    __syncthreads();

    int wv   = tid >> 6;
    int lane = tid & 63;
    int g    = lane >> 3;
    int l8   = lane & 7;
    int r0   = wv * 32 + g * 4;
    int col4 = l8 * 4;

    float acc[4][4];
#pragma unroll
    for (int i = 0; i < 4; i++)
#pragma unroll
        for (int c = 0; c < 4; c++) acc[i][c] = 0.f;

    const float4* H4  = (const float4*)Hl;  // row stride 11 float4
    const float4* Wl4 = (const float4*)Wl;

#pragma unroll
    for (int kq = 0; kq < 8; kq++) {
        float4 w0 = Wl4[(kq * 4 + 0) * 8 + l8];
        float4 w1 = Wl4[(kq * 4 + 1) * 8 + l8];
        float4 w2 = Wl4[(kq * 4 + 2) * 8 + l8];
        float4 w3 = Wl4[(kq * 4 + 3) * 8 + l8];
#pragma unroll
        for (int i = 0; i < 4; i++) {
            float4 hv = H4[(r0 + i) * 11 + kq];
            acc[i][0] += hv.x * w0.x; acc[i][1] += hv.x * w0.y;
            acc[i][2] += hv.x * w0.z; acc[i][3] += hv.x * w0.w;
            acc[i][0] += hv.y * w1.x; acc[i][1] += hv.y * w1.y;
            acc[i][2] += hv.y * w1.z; acc[i][3] += hv.y * w1.w;
            acc[i][0] += hv.z * w2.x; acc[i][1] += hv.z * w2.y;
            acc[i][2] += hv.z * w2.z; acc[i][3] += hv.z * w2.w;
            acc[i][0] += hv.w * w3.x; acc[i][1] += hv.w * w3.y;
            acc[i][2] += hv.w * w3.z; acc[i][3] += hv.w * w3.w;
        }
    }

    float4 alo = ((const float4*)a)[l8];
    float4 ahi = ((const float4*)a)[8 + l8];
#pragma unroll
    for (int i = 0; i < 4; i++) {
        int row = rowBase + r0 + i;
        if (row < N) {
            float4 zv = make_float4(acc[i][0], acc[i][1], acc[i][2], acc[i][3]);
            *(float4*)&z[(size_t)row * 32 + col4] = zv;
            float ps = zv.x * alo.x + zv.y * alo.y + zv.z * alo.z + zv.w * alo.w;
            float pd = zv.x * ahi.x + zv.y * ahi.y + zv.z * ahi.z + zv.w * ahi.w;
            ps += __shfl_xor(ps, 1, 64); ps += __shfl_xor(ps, 2, 64); ps += __shfl_xor(ps, 4, 64);
            pd += __shfl_xor(pd, 1, 64); pd += __shfl_xor(pd, 2, 64); pd += __shfl_xor(pd, 4, 64);
            if (l8 == 0) { s_src[row] = ps; s_dst[row] = pd; }
        }
    }
}

// layer 3: z3[i] = h[i]·W3, s_src = z*a0, s_dst = z*a1
__global__ __launch_bounds__(256) void gemm3_kernel(
    const float* __restrict__ h, const float* __restrict__ W,
    const float* __restrict__ a, float* __restrict__ z,
    float* __restrict__ s_src, float* __restrict__ s_dst, int N)
{
    int i = blockIdx.x * 256 + threadIdx.x;
    if (i >= N) return;
    const float4* hp = (const float4*)(h + (size_t)i * 32);
    const float4* wp = (const float4*)W;
    float acc = 0.f;
#pragma unroll
    for (int c = 0; c < 8; c++) {
        float4 v = hp[c];
        float4 w = wp[c];
        acc += v.x * w.x + v.y * w.y + v.z * w.z + v.w * w.w;
    }
    z[i] = acc;
    s_src[i] = acc * a[0];
    s_dst[i] = acc * a[1];
}

// ============================================================================
// CSR construction via per-dst linked list
// ============================================================================

__global__ __launch_bounds__(256) void build_ll_kernel(
    const int* __restrict__ src, const int* __restrict__ dst,
    int* __restrict__ head, int2* __restrict__ ll, int E)
{
    int k = blockIdx.x * 256 + threadIdx.x;
    if (k >= E) return;
    int d = dst[k];
    int s = src[k];
    int old = atomicExch(&head[d], k);
    ll[k] = make_int2(old, s);
}

__global__ __launch_bounds__(256) void walk_count_kernel(
    const int* __restrict__ head, const int2* __restrict__ ll,
    int* __restrict__ deg, int N)
{
    int i = blockIdx.x * 256 + threadIdx.x;
    if (i >= N) return;
    int c = 0;
    int e = head[i];
    while (e >= 0) { c++; e = ll[e].x; }
    deg[i] = c;
}

__global__ __launch_bounds__(256) void scan1_kernel(
    const int* __restrict__ deg, int* __restrict__ offsets,
    int* __restrict__ blockSums, int N)
{
    __shared__ int tmp[256];
    int tid = threadIdx.x;
    int i = blockIdx.x * 256 + tid;
    int v = (i < N) ? deg[i] : 0;
    tmp[tid] = v;
    __syncthreads();
#pragma unroll
    for (int off = 1; off < 256; off <<= 1) {
        int t = (tid >= off) ? tmp[tid - off] : 0;
        __syncthreads();
        tmp[tid] += t;
        __syncthreads();
    }
    if (i < N) offsets[i] = tmp[tid];
    if (tid == 255) blockSums[blockIdx.x] = tmp[255];
}

__global__ __launch_bounds__(512) void scan2_kernel(int* __restrict__ blockSums, int nb)
{
    __shared__ int tmp[512];
    int tid = threadIdx.x;
    int v = (tid < nb) ? blockSums[tid] : 0;
    tmp[tid] = v;
    __syncthreads();
#pragma unroll
    for (int off = 1; off < 512; off <<= 1) {
        int t = (tid >= off) ? tmp[tid - off] : 0;
        __syncthreads();
        tmp[tid] += t;
        __syncthreads();
    }
    if (tid < nb) blockSums[tid] = tmp[tid] - v;
}

__global__ __launch_bounds__(256) void scan3_kernel(
    const int* __restrict__ deg, const int* __restrict__ blockSums,
    int* __restrict__ offsets, int N, int E)
{
    int i = blockIdx.x * 256 + threadIdx.x;
    if (i < N) {
        offsets[i] = offsets[i] - deg[i] + blockSums[i >> 8];
    }
    if (i == 0) offsets[N] = E;
}

__global__ __launch_bounds__(256) void walk_write_kernel(
    const int* __restrict__ head, const int2* __restrict__ ll,
    const int* __restrict__ offsets, int* __restrict__ csr_src, int N)
{
    int i = blockIdx.x * 256 + threadIdx.x;
    if (i >= N) return;
    int p = offsets[i];
    int e = head[i];
    while (e >= 0) {
        int2 v = ll[e];
        csr_src[p++] = v.y;
        e = v.x;
    }
}

// ============================================================================
// Attention weights: thread-per-node, segment max + exp + denom. All softmax
// math here so the gather kernels below are branch-free streams.
// ============================================================================

__global__ __launch_bounds__(256) void attn_w_kernel(
    const int* __restrict__ offsets, const int* __restrict__ csr_src,
    const float* __restrict__ s_src, const float* __restrict__ s_dst,
    float* __restrict__ w_csr, float* __restrict__ rden, int N)
{
    int i = blockIdx.x * 256 + threadIdx.x;
    if (i >= N) return;
    int beg = offsets[i], end = offsets[i + 1];
    float sd = s_dst[i];

    float m = -3.0e38f;
    for (int p = beg; p < end; ++p) {
        int s = csr_src[p];
        float e = s_src[s] + sd;
        e = (e > 0.f) ? e : NEG_SLOPE * e;
        w_csr[p] = e;
        m = fmaxf(m, e);
    }
    float l = 0.f;
    for (int p = beg; p < end; ++p) {
        float w = __expf(w_csr[p] - m);
        l += w;
        w_csr[p] = w;
    }
    rden[i] = 1.f / fmaxf(l, 1e-9f);
}

// ============================================================================
// Weighted aggregation: branch-free SpMM row-gather, 4x unrolled
// ============================================================================

__global__ __launch_bounds__(256) void agg32_w_kernel(
    const int* __restrict__ offsets, const int* __restrict__ csr_src,
    const float* __restrict__ w_csr, const float* __restrict__ rden,
    const float* __restrict__ z, float* __restrict__ h, int N)
{
    int node = blockIdx.x * 8 + (threadIdx.x >> 5);
    int col  = threadIdx.x & 31;
    if (node >= N) return;

    int beg = offsets[node], end = offsets[node + 1];
    float o = 0.f;
    int p = beg;
    for (; p + 3 < end; p += 4) {
        int s0 = csr_src[p],     s1 = csr_src[p + 1];
        int s2 = csr_src[p + 2], s3 = csr_src[p + 3];
        float w0 = w_csr[p],     w1 = w_csr[p + 1];
        float w2 = w_csr[p + 2], w3 = w_csr[p + 3];
        float z0 = z[(size_t)s0 * 32 + col];
        float z1 = z[(size_t)s1 * 32 + col];
        float z2 = z[(size_t)s2 * 32 + col];
        float z3 = z[(size_t)s3 * 32 + col];
        o += w0 * z0;
        o += w1 * z1;
        o += w2 * z2;
        o += w3 * z3;
    }
    for (; p < end; ++p)
        o += w_csr[p] * z[(size_t)csr_src[p] * 32 + col];

    float v = o * rden[node];
    h[(size_t)node * 32 + col] = (v > 0.f) ? v : 0.f;  // relu
}

__global__ __launch_bounds__(256) void agg1_w_kernel(
    const int* __restrict__ offsets, const int* __restrict__ csr_src,
    const float* __restrict__ w_csr, const float* __restrict__ rden,
    const float* __restrict__ z, float* __restrict__ out, int N)
{
    int node = blockIdx.x * 256 + threadIdx.x;
    if (node >= N) return;

    int beg = offsets[node], end = offsets[node + 1];
    float o = 0.f;
    int p = beg;
    for (; p + 3 < end; p += 4) {
        int s0 = csr_src[p],     s1 = csr_src[p + 1];
        int s2 = csr_src[p + 2], s3 = csr_src[p + 3];
        float w0 = w_csr[p],     w1 = w_csr[p + 1];
        float w2 = w_csr[p + 2], w3 = w_csr[p + 3];
        o += w0 * z[s0];
        o += w1 * z[s1];
        o += w2 * z[s2];
        o += w3 * z[s3];
    }
    for (; p < end; ++p)
        o += w_csr[p] * z[csr_src[p]];

    float v = o * rden[node];
    out[node] = 1.f / (1.f + __expf(-v));  // sigmoid
}

// ============================================================================

extern "C" void kernel_launch(void* const* d_in, const int* in_sizes, int n_in,
                              void* d_out, int out_size, void* d_ws, size_t ws_size,
                              hipStream_t stream)
{
    const float* feature = (const float*)d_in[0];
    const int*   src     = (const int*)d_in[1];
    const int*   dst     = (const int*)d_in[2];
    const float* W1      = (const float*)d_in[3];
    const float* a1      = (const float*)d_in[4];
    const float* W2      = (const float*)d_in[5];
    const float* a2      = (const float*)d_in[6];
    const float* W3      = (const float*)d_in[7];
    const float* a3      = (const float*)d_in[8];
    float* out = (float*)d_out;

    const int N = in_sizes[0] / 128;
    const int E = in_sizes[1];

    // ---- workspace layout ----
    char* p = (char*)d_ws;
    float* zbuf    = (float*)p;  p += (size_t)N * 32 * sizeof(float);
    float* hbuf    = (float*)p;  p += (size_t)N * 32 * sizeof(float);
    float* s_src   = (float*)p;  p += (size_t)N * sizeof(float);
    float* s_dst   = (float*)p;  p += (size_t)N * sizeof(float);
    float* rden    = (float*)p;  p += (size_t)N * sizeof(float);
    int*   head    = (int*)p;    p += (size_t)N * sizeof(int);
    int*   deg     = (int*)p;    p += (size_t)N * sizeof(int);
    int*   offsets = (int*)p;    p += ((size_t)N + 1) * sizeof(int);
    int*   blockSums = (int*)p;  p += 512 * sizeof(int);
    int2*  ll      = (int2*)p;   p += (size_t)E * sizeof(int2);
    int*   csr_src = (int*)p;    p += (size_t)E * sizeof(int);
    float* w_csr   = (float*)p;  p += (size_t)E * sizeof(float);

    const int nodeBlocks8  = (N + 7) / 8;
    const int nodeBlocks   = (N + 255) / 256;
    const int edgeBlocks   = (E + 255) / 256;
    const int scanBlocks   = (N + 255) / 256;
    const int gemmBlocks64 = (N + 63) / 64;

    // ---- build CSR once via linked list ----
    hipMemsetAsync(head, 0xFF, (size_t)N * sizeof(int), stream);
    hipLaunchKernelGGL(build_ll_kernel, dim3(edgeBlocks), dim3(256), 0, stream,
                       src, dst, head, ll, E);
    hipLaunchKernelGGL(walk_count_kernel, dim3(nodeBlocks), dim3(256), 0, stream,
                       head, ll, deg, N);
    hipLaunchKernelGGL(scan1_kernel, dim3(scanBlocks), dim3(256), 0, stream,
                       deg, offsets, blockSums, N);
    hipLaunchKernelGGL(scan2_kernel, dim3(1), dim3(512), 0, stream,
                       blockSums, scanBlocks);
    hipLaunchKernelGGL(scan3_kernel, dim3(scanBlocks), dim3(256), 0, stream,
                       deg, blockSums, offsets, N, E);
    hipLaunchKernelGGL(walk_write_kernel, dim3(nodeBlocks), dim3(256), 0, stream,
                       head, ll, offsets, csr_src, N);

    // ---- layer 1 (128 -> 32, relu) ----
    hipLaunchKernelGGL(gemm1_kernel, dim3(gemmBlocks64), dim3(128), 0, stream,
                       feature, W1, a1, zbuf, s_src, s_dst, N);
    hipLaunchKernelGGL(attn_w_kernel, dim3(nodeBlocks), dim3(256), 0, stream,
                       offsets, csr_src, s_src, s_dst, w_csr, rden, N);
    hipLaunchKernelGGL(agg32_w_kernel, dim3(nodeBlocks8), dim3(256), 0, stream,
                       offsets, csr_src, w_csr, rden, zbuf, hbuf, N);

    // ---- layer 2 (32 -> 32, relu) ----
    hipLaunchKernelGGL(gemm2_kernel, dim3(gemmBlocks64), dim3(128), 0, stream,
                       hbuf, W2, a2, zbuf, s_src, s_dst, N);
    hipLaunchKernelGGL(attn_w_kernel, dim3(nodeBlocks), dim3(256), 0, stream,
                       offsets, csr_src, s_src, s_dst, w_csr, rden, N);
    hipLaunchKernelGGL(agg32_w_kernel, dim3(nodeBlocks8), dim3(256), 0, stream,
                       offsets, csr_src, w_csr, rden, zbuf, hbuf, N);

    // ---- layer 3 (32 -> 1, sigmoid) ----
    hipLaunchKernelGGL(gemm3_kernel, dim3(nodeBlocks), dim3(256), 0, stream,
                       hbuf, W3, a3, zbuf, s_src, s_dst, N);  // zbuf[:N] = z3
    hipLaunchKernelGGL(attn_w_kernel, dim3(nodeBlocks), dim3(256), 0, stream,
                       offsets, csr_src, s_src, s_dst, w_csr, rden, N);
    hipLaunchKernelGGL(agg1_w_kernel, dim3(nodeBlocks), dim3(256), 0, stream,
                       offsets, csr_src, w_csr, rden, zbuf, out, N);
}